// Round 3
// baseline (7330.721 us; speedup 1.0000x reference)
//
#include <hip/hip_runtime.h>
#include <hip/hip_bf16.h>

// Problem constants
#define BATCH   64
#define SEQ     512
#define DMODEL  256
#define HIDDEN  512
#define G3      1536      // 3*HIDDEN
#define NBLK    128       // scan blocks; 512 hidden units / 128 = 4 units/block
#define UPB     4         // units per block
#define CPB     12        // Wh columns per block (3 gates * UPB)

typedef unsigned long long u64;
typedef unsigned int u32;

// ---------------------------------------------------------------------------
// Pack Wh slices: whp[blk][c][k] = Wh[k][ g*512 + blk*4 + u ]  (c = g*4+u)
// Contiguous in k so the scan kernel's wave-uniform weight reads scalarize
// (s_load from hot L2; nothing in the scan loop invalidates L2 anymore).
// ---------------------------------------------------------------------------
__global__ __launch_bounds__(512) void prep_wh(const float* __restrict__ Wh,
                                               float* __restrict__ whp) {
    int t = blockIdx.x * 512 + threadIdx.x;      // 0 .. 786431
    int k   = t & 511;
    int cb  = t >> 9;          // blk*12 + c
    int c   = cb % 12;
    int blk = cb / 12;
    int u = c & 3, g = c >> 2;
    whp[t] = Wh[(long)k * G3 + g * HIDDEN + blk * UPB + u];
}

// ---------------------------------------------------------------------------
// xg GEMM, TRANSPOSED output: xgS[col][s][b] = emb[ids[b][s]] . Wx[:,col] + bx[col]
// so the scan's per-step gate reads are coalesced (b fastest).
// Block = (col-tile nb, timestep s). 64 cols x 64 batches, K=256.
// ---------------------------------------------------------------------------
__global__ __launch_bounds__(256) void xg_gemm(const int* __restrict__ ids,
                                               const float* __restrict__ emb,
                                               const float* __restrict__ Wx,
                                               const float* __restrict__ bx,
                                               float* __restrict__ xgS) {
    __shared__ float Es[64][68];   // Es[k][b], padded
    __shared__ float Ws[64][68];   // Ws[k][c], padded
    __shared__ int   sids[64];

    const int tid = threadIdx.x;
    const int nb = blockIdx.x;     // col tile 0..23
    const int s  = blockIdx.y;     // timestep 0..511
    const int tn = tid & 15;
    const int tm = tid >> 4;

    if (tid < 64) sids[tid] = ids[tid * SEQ + s];   // id for batch=tid at step s
    __syncthreads();

    float acc[4][4];               // acc[i=col][j=b]
#pragma unroll
    for (int i = 0; i < 4; ++i)
#pragma unroll
        for (int j = 0; j < 4; ++j) acc[i][j] = 0.f;

    for (int kb = 0; kb < 256; kb += 64) {
#pragma unroll
        for (int p = 0; p < 4; ++p) {
            int b = p * 16 + tm;
            float4 av = *(const float4*)(emb + (long)sids[b] * DMODEL + kb + tn * 4);
            Es[tn * 4 + 0][b] = av.x;
            Es[tn * 4 + 1][b] = av.y;
            Es[tn * 4 + 2][b] = av.z;
            Es[tn * 4 + 3][b] = av.w;
            int krow = p * 16 + tm;
            float4 wv = *(const float4*)(Wx + (long)(kb + krow) * G3 + nb * 64 + tn * 4);
            *(float4*)&Ws[krow][tn * 4] = wv;
        }
        __syncthreads();
#pragma unroll
        for (int k = 0; k < 64; ++k) {
            float4 w4 = *(const float4*)&Ws[k][tm * 4];
            float4 e4 = *(const float4*)&Es[k][tn * 4];
            float ww[4] = {w4.x, w4.y, w4.z, w4.w};
            float ee[4] = {e4.x, e4.y, e4.z, e4.w};
#pragma unroll
            for (int i = 0; i < 4; ++i)
#pragma unroll
                for (int j = 0; j < 4; ++j)
                    acc[i][j] = fmaf(ww[i], ee[j], acc[i][j]);
        }
        __syncthreads();
    }

#pragma unroll
    for (int i = 0; i < 4; ++i) {
        int col = nb * 64 + tm * 4 + i;
        float bxi = bx[col];
        float4 o;
        o.x = acc[i][0] + bxi;
        o.y = acc[i][1] + bxi;
        o.z = acc[i][2] + bxi;
        o.w = acc[i][3] + bxi;
        *(float4*)(xgS + (long)col * (SEQ * BATCH) + s * 64 + tn * 4) = o;
    }
}

// ---------------------------------------------------------------------------
// GRU scan v3: tagged-h handshake, NO flag barrier.
// Each h value is stored as a packed u64: (tag = t+1) << 32 | f32 bits.
// Consumers bulk-load their k-slice and spin only on stale entries. This
// removes: the producer-side store drain before a flag, the flag store, the
// flag snoop-propagation RTT, and the 1024-wave flag-line contention.
// ABA-safe: a block writes tag t+2 only after reading ALL tag-(t+1) values,
// which transitively requires every block to have consumed tag t -> a
// consumer polling slot[t&1] can only observe tags <= t. Deadlock-free with
// all 128 blocks co-resident (128 <= 256 CUs, single kernel).
// ---------------------------------------------------------------------------
__global__ __launch_bounds__(512, 2) void gru_scan(const float* __restrict__ whp,
                                                   const float* __restrict__ xgS,
                                                   const float* __restrict__ bh,
                                                   u64* hp) {
    const int tid = threadIdx.x;
    const int blk = blockIdx.x;
    const int b   = tid & 63;                                 // lane = batch
    const int wu  = __builtin_amdgcn_readfirstlane(tid >> 6); // wave 0..7

    __shared__ float part[8][CPB][64];   // 24 KB partial sums
    __shared__ float hl[UPB][64];        // this block's own h slice (hprev)

    const float* wb = whp + blk * (CPB * HIDDEN) + wu * 64;   // + c*512 + i

    const int gu = tid >> 6;
    int jg = 0;
    float bhr = 0.f, bhz = 0.f, bhn = 0.f;
    const float* xr_p = nullptr; const float* xz_p = nullptr; const float* xn_p = nullptr;
    if (tid < 256) {
        jg  = blk * UPB + gu;
        bhr = bh[jg];
        bhz = bh[HIDDEN + jg];
        bhn = bh[2 * HIDDEN + jg];
        xr_p = xgS + (long)jg * (SEQ * BATCH) + b;
        xz_p = xgS + (long)(HIDDEN + jg) * (SEQ * BATCH) + b;
        xn_p = xgS + (long)(2 * HIDDEN + jg) * (SEQ * BATCH) + b;
        hl[gu][b] = 0.f;                 // h0 = 0
    }
    __syncthreads();

#pragma unroll 1
    for (int t = 0; t < SEQ; ++t) {
        u64* hcur = hp + (t & 1) * (HIDDEN * BATCH);
        u64* hnxt = hp + ((t + 1) & 1) * (HIDDEN * BATCH);

        // coalesced gate-input loads (xgS[col][t][b]); in flight during poll
        float xr = 0.f, xz = 0.f, xn = 0.f, hprev = 0.f;
        if (tid < 256) {
            xr = xr_p[t * 64];
            xz = xz_p[t * 64];
            xn = xn_p[t * 64];
            hprev = hl[gu][b];
        }

        if (t > 0) {
            const u64* hc = hcur + (wu * 64) * 64 + b;
            const u32 want = (u32)t;
            u64 v[64];
#pragma unroll
            for (int i = 0; i < 64; ++i)
                v[i] = __hip_atomic_load(hc + (long)i * 64, __ATOMIC_RELAXED,
                                         __HIP_MEMORY_SCOPE_AGENT);
            // spin only on stale entries
            bool ok = false;
            while (!ok) {
                ok = true;
#pragma unroll
                for (int i = 0; i < 64; ++i) {
                    if ((u32)(v[i] >> 32) != want) {
                        v[i] = __hip_atomic_load(hc + (long)i * 64, __ATOMIC_RELAXED,
                                                 __HIP_MEMORY_SCOPE_AGENT);
                        ok = false;
                    }
                }
            }

            float acc[CPB];
#pragma unroll
            for (int c = 0; c < CPB; ++c) acc[c] = 0.f;
#pragma unroll
            for (int i = 0; i < 64; ++i) {
                float hv = __uint_as_float((u32)v[i]);
#pragma unroll
                for (int c = 0; c < CPB; ++c)
                    acc[c] = fmaf(hv, wb[c * HIDDEN + i], acc[c]);
            }
#pragma unroll
            for (int c = 0; c < CPB; ++c) part[wu][c][b] = acc[c];
        } else {
            // h0 == 0 => hg = bh
#pragma unroll
            for (int c = 0; c < CPB; ++c) part[wu][c][b] = 0.f;
        }
        __syncthreads();

        if (tid < 256) {
            float hgr = bhr, hgz = bhz, hgn = bhn;
#pragma unroll
            for (int ww = 0; ww < 8; ++ww) {
                hgr += part[ww][gu][b];
                hgz += part[ww][4 + gu][b];
                hgn += part[ww][8 + gu][b];
            }
            float r  = 1.f / (1.f + expf(-(xr + hgr)));
            float z  = 1.f / (1.f + expf(-(xz + hgz)));
            float nn = tanhf(xn + r * hgn);
            float hnew = (1.f - z) * nn + z * hprev;
            u64 pk = ((u64)(u32)(t + 1) << 32) | (u64)__float_as_uint(hnew);
            __hip_atomic_store(&hnxt[jg * 64 + b], pk, __ATOMIC_RELAXED,
                               __HIP_MEMORY_SCOPE_AGENT);
            hl[gu][b] = hnew;
        }
        // keeps next iteration's part[] writes from racing the gate reads
        __syncthreads();
    }
}

// ---------------------------------------------------------------------------
// head: logits[b][n] = sum_k h[k][b] * Wo[k][n] + bo[n]
// Final h (tag 512) sits in slot 0 of hp; value is the low 32 bits.
// ---------------------------------------------------------------------------
__global__ void head_kernel(const u64* __restrict__ hT,
                            const float* __restrict__ Wo,
                            const float* __restrict__ bo,
                            float* __restrict__ out) {
    int tid = threadIdx.x;        // 128 threads
    int b = tid >> 1, n = tid & 1;
    float acc = bo[n];
#pragma unroll 8
    for (int k = 0; k < HIDDEN; ++k)
        acc = fmaf(__uint_as_float((u32)hT[k * 64 + b]), Wo[k * 2 + n], acc);
    out[b * 2 + n] = acc;
}

// ---------------------------------------------------------------------------
extern "C" void kernel_launch(void* const* d_in, const int* in_sizes, int n_in,
                              void* d_out, int out_size, void* d_ws, size_t ws_size,
                              hipStream_t stream) {
    (void)in_sizes; (void)n_in; (void)out_size; (void)ws_size;
    const int*   ids = (const int*)  d_in[0];
    const float* emb = (const float*)d_in[1];
    const float* Wx  = (const float*)d_in[2];
    const float* Wh  = (const float*)d_in[3];
    const float* bx  = (const float*)d_in[4];
    const float* bh  = (const float*)d_in[5];
    const float* Wo  = (const float*)d_in[6];
    const float* bo  = (const float*)d_in[7];
    float* out = (float*)d_out;

    char* ws = (char*)d_ws;
    // ws layout: [hp 2*512*64 u64 = 512KB][whp 3MB][xgS 201MB]
    // hp needs NO init: poison 0xAAAAAAAA never matches a tag in [1,512].
    u64*   hpd  = (u64*)ws;
    float* whp  = (float*)(ws + 2 * HIDDEN * BATCH * sizeof(u64));
    float* xgS  = (float*)(ws + 2 * HIDDEN * BATCH * sizeof(u64) + NBLK * CPB * HIDDEN * 4);

    prep_wh<<<dim3(1536), dim3(512), 0, stream>>>(Wh, whp);
    xg_gemm<<<dim3(24, 512), dim3(256), 0, stream>>>(ids, emb, Wx, bx, xgS);
    gru_scan<<<dim3(NBLK), dim3(512), 0, stream>>>(whp, xgS, bh, hpd);
    head_kernel<<<dim3(1), dim3(128), 0, stream>>>(hpd, Wo, bo, out);
}

// Round 4
// 6007.377 us; speedup vs baseline: 1.2203x; 1.2203x over previous
//
#include <hip/hip_runtime.h>
#include <hip/hip_bf16.h>

// Problem constants
#define BATCH   64
#define SEQ     512
#define DMODEL  256
#define HIDDEN  512
#define G3      1536      // 3*HIDDEN
#define NBLK    128       // scan blocks; 512 hidden units / 128 = 4 units/block
#define UPB     4         // units per block
#define CPB     12        // Wh columns per block (3 gates * UPB)

typedef unsigned int u32;

// ---------------------------------------------------------------------------
// Pack Wh slices: whp[blk][c][k] = Wh[k][ g*512 + blk*4 + u ]  (c = g*4+u)
// Contiguous in k so the scan kernel's wave-uniform weight reads scalarize
// (s_load from hot L2; nothing in the scan loop invalidates L2).
// ---------------------------------------------------------------------------
__global__ __launch_bounds__(512) void prep_wh(const float* __restrict__ Wh,
                                               float* __restrict__ whp) {
    int t = blockIdx.x * 512 + threadIdx.x;      // 0 .. 786431
    int k   = t & 511;
    int cb  = t >> 9;          // blk*12 + c
    int c   = cb % 12;
    int blk = cb / 12;
    int u = c & 3, g = c >> 2;
    whp[t] = Wh[(long)k * G3 + g * HIDDEN + blk * UPB + u];
}

// ---------------------------------------------------------------------------
// Zero barrier flags with agent-scope stores (the scan polls with
// L2-bypassing loads; plain memset could leave zeros dirty in one L2).
// ---------------------------------------------------------------------------
__global__ void init_flags(unsigned* flags) {
    __hip_atomic_store(&flags[threadIdx.x], 0u, __ATOMIC_RELAXED,
                       __HIP_MEMORY_SCOPE_AGENT);
}

// ---------------------------------------------------------------------------
// xg GEMM, TRANSPOSED output: xgS[col][s][b] = emb[ids[b][s]] . Wx[:,col] + bx[col]
// so the scan's per-step gate reads are coalesced (b fastest).
// ---------------------------------------------------------------------------
__global__ __launch_bounds__(256) void xg_gemm(const int* __restrict__ ids,
                                               const float* __restrict__ emb,
                                               const float* __restrict__ Wx,
                                               const float* __restrict__ bx,
                                               float* __restrict__ xgS) {
    __shared__ float Es[64][68];   // Es[k][b], padded
    __shared__ float Ws[64][68];   // Ws[k][c], padded
    __shared__ int   sids[64];

    const int tid = threadIdx.x;
    const int nb = blockIdx.x;     // col tile 0..23
    const int s  = blockIdx.y;     // timestep 0..511
    const int tn = tid & 15;
    const int tm = tid >> 4;

    if (tid < 64) sids[tid] = ids[tid * SEQ + s];   // id for batch=tid at step s
    __syncthreads();

    float acc[4][4];               // acc[i=col][j=b]
#pragma unroll
    for (int i = 0; i < 4; ++i)
#pragma unroll
        for (int j = 0; j < 4; ++j) acc[i][j] = 0.f;

    for (int kb = 0; kb < 256; kb += 64) {
#pragma unroll
        for (int p = 0; p < 4; ++p) {
            int b = p * 16 + tm;
            float4 av = *(const float4*)(emb + (long)sids[b] * DMODEL + kb + tn * 4);
            Es[tn * 4 + 0][b] = av.x;
            Es[tn * 4 + 1][b] = av.y;
            Es[tn * 4 + 2][b] = av.z;
            Es[tn * 4 + 3][b] = av.w;
            int krow = p * 16 + tm;
            float4 wv = *(const float4*)(Wx + (long)(kb + krow) * G3 + nb * 64 + tn * 4);
            *(float4*)&Ws[krow][tn * 4] = wv;
        }
        __syncthreads();
#pragma unroll
        for (int k = 0; k < 64; ++k) {
            float4 w4 = *(const float4*)&Ws[k][tm * 4];
            float4 e4 = *(const float4*)&Es[k][tn * 4];
            float ww[4] = {w4.x, w4.y, w4.z, w4.w};
            float ee[4] = {e4.x, e4.y, e4.z, e4.w};
#pragma unroll
            for (int i = 0; i < 4; ++i)
#pragma unroll
                for (int j = 0; j < 4; ++j)
                    acc[i][j] = fmaf(ww[i], ee[j], acc[i][j]);
        }
        __syncthreads();
    }

#pragma unroll
    for (int i = 0; i < 4; ++i) {
        int col = nb * 64 + tm * 4 + i;
        float bxi = bx[col];
        float4 o;
        o.x = acc[i][0] + bxi;
        o.y = acc[i][1] + bxi;
        o.z = acc[i][2] + bxi;
        o.w = acc[i][3] + bxi;
        *(float4*)(xgS + (long)col * (SEQ * BATCH) + s * 64 + tn * 4) = o;
    }
}

// ---------------------------------------------------------------------------
// GRU scan v4: single-poller flag barrier + single-shot h loads.
// Insight from v2/v3: both landed at ~13.2 us/step because ALL 1024 waves
// polled agent-scope locations continuously, congesting the coherence
// fabric. Here only wave 0 of each block polls (128 pollers on 4 cache
// lines); the other waves park at s_barrier (zero traffic). h loads are
// issued exactly once per step, after the release guarantees freshness.
// Ordering: producer h-stores drained by sync2's vmcnt(0) before the flag
// store; consumer h-loads issue after sync3 (post-poll), and agent-scope
// relaxed loads bypass L1/L2 so they read the coherence point.
// Deadlock-free: 128 blocks co-resident (<= 256 CUs, one kernel).
// ---------------------------------------------------------------------------
__global__ __launch_bounds__(512, 2) void gru_scan(const float* __restrict__ whp,
                                                   const float* __restrict__ xgS,
                                                   const float* __restrict__ bh,
                                                   float* hbuf,
                                                   unsigned* flags) {
    const int tid = threadIdx.x;
    const int blk = blockIdx.x;
    const int b   = tid & 63;                                 // lane = batch
    const int wu  = __builtin_amdgcn_readfirstlane(tid >> 6); // wave 0..7

    __shared__ float part[8][CPB][64];   // 24 KB partial sums
    __shared__ float hl[UPB][64];        // this block's own h slice (hprev)

    const float* wb = whp + blk * (CPB * HIDDEN) + wu * 64;   // + c*512 + i

    const int gu = tid >> 6;
    int jg = 0;
    float bhr = 0.f, bhz = 0.f, bhn = 0.f;
    const float* xr_p = nullptr; const float* xz_p = nullptr; const float* xn_p = nullptr;
    if (tid < 256) {
        jg  = blk * UPB + gu;
        bhr = bh[jg];
        bhz = bh[HIDDEN + jg];
        bhn = bh[2 * HIDDEN + jg];
        xr_p = xgS + (long)jg * (SEQ * BATCH) + b;
        xz_p = xgS + (long)(HIDDEN + jg) * (SEQ * BATCH) + b;
        xn_p = xgS + (long)(2 * HIDDEN + jg) * (SEQ * BATCH) + b;
        hl[gu][b] = 0.f;                 // h0 = 0
    }
    __syncthreads();

#pragma unroll 1
    for (int t = 0; t < SEQ; ++t) {
        float* hcur = hbuf + (t & 1) * (HIDDEN * BATCH);
        float* hnxt = hbuf + ((t + 1) & 1) * (HIDDEN * BATCH);

        // coalesced gate-input loads (xgS[col][t][b]); read-only, cached
        float xr = 0.f, xz = 0.f, xn = 0.f, hprev = 0.f;
        if (tid < 256) {
            xr = xr_p[t * 64];
            xz = xz_p[t * 64];
            xn = xn_p[t * 64];
            hprev = hl[gu][b];
        }

        if (t > 0) {
            // single-shot slice load: freshness guaranteed by prior release
            const float* hc = hcur + (wu * 64) * 64 + b;
            float hreg[64];
#pragma unroll
            for (int i = 0; i < 64; ++i)
                hreg[i] = __hip_atomic_load(hc + (long)i * 64, __ATOMIC_RELAXED,
                                            __HIP_MEMORY_SCOPE_AGENT);

            float acc[CPB];
#pragma unroll
            for (int c = 0; c < CPB; ++c) acc[c] = 0.f;
#pragma unroll
            for (int i = 0; i < 64; ++i) {
                float hv = hreg[i];
#pragma unroll
                for (int c = 0; c < CPB; ++c)
                    acc[c] = fmaf(hv, wb[c * HIDDEN + i], acc[c]);
            }
#pragma unroll
            for (int c = 0; c < CPB; ++c) part[wu][c][b] = acc[c];
        } else {
            // h0 == 0 => hg = bh
#pragma unroll
            for (int c = 0; c < CPB; ++c) part[wu][c][b] = 0.f;
        }
        __syncthreads();                                   // sync1: partials ready

        if (tid < 256) {
            float hgr = bhr, hgz = bhz, hgn = bhn;
#pragma unroll
            for (int ww = 0; ww < 8; ++ww) {
                hgr += part[ww][gu][b];
                hgz += part[ww][4 + gu][b];
                hgn += part[ww][8 + gu][b];
            }
            float r  = 1.f / (1.f + expf(-(xr + hgr)));
            float z  = 1.f / (1.f + expf(-(xz + hgz)));
            float nn = tanhf(xn + r * hgn);
            float hnew = (1.f - z) * nn + z * hprev;
            __hip_atomic_store(&hnxt[jg * 64 + b], hnew, __ATOMIC_RELAXED,
                               __HIP_MEMORY_SCOPE_AGENT);
            hl[gu][b] = hnew;
        }
        __syncthreads();                                   // sync2: drains h stores

        if (t < SEQ - 1) {
            if (tid == 0)
                __hip_atomic_store(&flags[blk], (unsigned)(t + 1),
                                   __ATOMIC_RELAXED, __HIP_MEMORY_SCOPE_AGENT);
            if (wu == 0) {
                // the ONLY polling wave in this block
                const unsigned tgt = (unsigned)(t + 1);
                for (;;) {
                    unsigned f0 = __hip_atomic_load(&flags[b], __ATOMIC_RELAXED,
                                                    __HIP_MEMORY_SCOPE_AGENT);
                    unsigned f1 = __hip_atomic_load(&flags[64 + b], __ATOMIC_RELAXED,
                                                    __HIP_MEMORY_SCOPE_AGENT);
                    if (__all(f0 >= tgt && f1 >= tgt)) break;
                    __builtin_amdgcn_s_sleep(1);
                }
            }
            __syncthreads();                               // sync3: release
            __builtin_amdgcn_fence(__ATOMIC_ACQUIRE, "workgroup"); // compiler order only
        }
    }
}

// ---------------------------------------------------------------------------
// head: logits[b][n] = sum_k h[k][b] * Wo[k][n] + bo[n]
// Final h (t=512) sits in slot 0 of hbuf.
// ---------------------------------------------------------------------------
__global__ void head_kernel(const float* __restrict__ hT,
                            const float* __restrict__ Wo,
                            const float* __restrict__ bo,
                            float* __restrict__ out) {
    int tid = threadIdx.x;        // 128 threads
    int b = tid >> 1, n = tid & 1;
    float acc = bo[n];
#pragma unroll 8
    for (int k = 0; k < HIDDEN; ++k)
        acc = fmaf(hT[k * 64 + b], Wo[k * 2 + n], acc);
    out[b * 2 + n] = acc;
}

// ---------------------------------------------------------------------------
extern "C" void kernel_launch(void* const* d_in, const int* in_sizes, int n_in,
                              void* d_out, int out_size, void* d_ws, size_t ws_size,
                              hipStream_t stream) {
    (void)in_sizes; (void)n_in; (void)out_size; (void)ws_size;
    const int*   ids = (const int*)  d_in[0];
    const float* emb = (const float*)d_in[1];
    const float* Wx  = (const float*)d_in[2];
    const float* Wh  = (const float*)d_in[3];
    const float* bx  = (const float*)d_in[4];
    const float* bh  = (const float*)d_in[5];
    const float* Wo  = (const float*)d_in[6];
    const float* bo  = (const float*)d_in[7];
    float* out = (float*)d_out;

    char* ws = (char*)d_ws;
    // ws layout: [flags 1KB][hbuf 2*512*64 f32 = 256KB][whp 3MB][xgS 201MB]
    // hbuf needs no init: t=0 skips the matvec (h0=0 handled analytically).
    unsigned* flags = (unsigned*)ws;
    float* hbuf = (float*)(ws + 1024);
    float* whp  = (float*)(ws + 1024 + 2 * HIDDEN * BATCH * 4);
    float* xgS  = (float*)(ws + 1024 + 2 * HIDDEN * BATCH * 4 + NBLK * CPB * HIDDEN * 4);

    init_flags<<<dim3(1), dim3(NBLK), 0, stream>>>(flags);
    prep_wh<<<dim3(1536), dim3(512), 0, stream>>>(Wh, whp);
    xg_gemm<<<dim3(24, 512), dim3(256), 0, stream>>>(ids, emb, Wx, bx, xgS);
    gru_scan<<<dim3(NBLK), dim3(512), 0, stream>>>(whp, xgS, bh, hbuf, flags);
    head_kernel<<<dim3(1), dim3(128), 0, stream>>>(hbuf, Wo, bo, out);
}